// Round 11
// baseline (239.521 us; speedup 1.0000x reference)
//
#include <hip/hip_runtime.h>
#include <hip/hip_bf16.h>
#include <stdint.h>

typedef __bf16 bf16_t;
typedef __bf16 bf16x8 __attribute__((ext_vector_type(8)));
typedef __bf16 bf16x4 __attribute__((ext_vector_type(4)));
typedef float  f32x4  __attribute__((ext_vector_type(4)));
typedef float  f32x16 __attribute__((ext_vector_type(16)));

#define AS_GLOBAL __attribute__((address_space(1)))
#define AS_LDS    __attribute__((address_space(3)))
#define VMW(N) asm volatile("s_waitcnt vmcnt(" #N ")" ::: "memory")

static constexpr int CCH   = 256;
static constexpr int HP    = 34;
static constexpr int PLANE = HP * HP;   // 1156 padded pixels per image

// ---------------- BN parameter folding ----------------
__global__ void prep_params_k(const float* g1, const float* b1, const float* m1, const float* v1,
                              const float* g2, const float* b2, const float* m2, const float* v2,
                              float* prm) {
  int i = threadIdx.x;
  float i1 = g1[i] * rsqrtf(v1[i] + 1e-5f);
  prm[i]       = i1;
  prm[256 + i] = b1[i] - m1[i] * i1;
  float i2 = g2[i] * rsqrtf(v2[i] + 1e-5f);
  prm[512 + i] = i2;
  prm[768 + i] = b2[i] - m2[i] * i2;
}

// ---------------- masked weights -> bf16, [khw][co][ci] ----------------
__global__ __launch_bounds__(256) void prep_weights_k(const float* __restrict__ w,
                                                      const float* __restrict__ msk,
                                                      bf16_t* __restrict__ out) {
  int idx = blockIdx.x * 256 + threadIdx.x;
  const float* wp = w + (long)idx * 9;
  const float* mp = msk + (long)idx * 9;
#pragma unroll
  for (int khw = 0; khw < 9; ++khw)
    out[khw * 65536 + idx] = (bf16_t)(wp[khw] * mp[khw]);
}

// ---------------- zero only the pad borders of both intermediates ----------------
__global__ __launch_bounds__(256) void zero_borders_k(bf16_t* __restrict__ t0p,
                                                      bf16_t* __restrict__ t1p) {
  const int bid = blockIdx.x;               // 128: image n = bid>>1, buffer = bid&1
  bf16_t* base = ((bid & 1) ? t1p : t0p) + (long)(bid >> 1) * PLANE * CCH;
  for (int i = threadIdx.x; i < 132 * 32; i += 256) {
    int pix = i >> 5, c16 = i & 31;
    int r, col;
    if (pix < 34)       { r = 0;           col = pix; }
    else if (pix < 68)  { r = 33;          col = pix - 34; }
    else if (pix < 100) { r = pix - 68 + 1; col = 0; }
    else                { r = pix - 100 + 1; col = 33; }
    *(f32x4*)&base[(r * HP + col) * CCH + c16 * 8] = f32x4{0.f, 0.f, 0.f, 0.f};
  }
}

// ------- relu(bn1(x)) -> bf16, NCHW -> channels-last padded [n][34*34][256] -------
__global__ __launch_bounds__(256) void prep_input_k(const float* __restrict__ x,
                                                    const float* __restrict__ prm,
                                                    bf16_t* __restrict__ t0p) {
  __shared__ __align__(16) bf16_t tile[64 * 256];
  const int tid = threadIdx.x;
  const int bid = blockIdx.x;
  const int n   = bid >> 4;
  const int p0  = (bid & 15) << 6;
  const int px    = tid & 63;
  const int cbase = tid >> 6;
  for (int r = 0; r < 64; ++r) {
    int ci = r * 4 + cbase;
    float v = x[((n * 256 + ci) << 10) + p0 + px];
    float y = fmaxf(v * prm[ci] + prm[256 + ci], 0.f);
    int byte = px * 512 + ((ci * 2) ^ ((px & 7) << 4));
    *(bf16_t*)((char*)tile + byte) = (bf16_t)y;
  }
  __syncthreads();
  for (int j = 0; j < 8; ++j) {
    int off  = j * 256 + tid;
    int pix  = off >> 5;
    int c16  = off & 31;
    int byte = pix * 512 + ((c16 * 16) ^ ((pix & 7) << 4));
    bf16x8 v = *(const bf16x8*)((char*)tile + byte);
    int p = p0 + pix;
    long gp = ((long)n * PLANE + ((p >> 5) + 1) * HP + (p & 31) + 1) * CCH + c16 * 8;
    *(bf16x8*)(t0p + gp) = v;
  }
}

// ---- implicit-GEMM 3x3 conv: A global->VGPR, B plane-major LDS, 32x32 MFMA ------
// Block 128co x 256px, 4 waves, wave 64co x 128px (2x4 tiles of 32x32).
// R11 changes vs R10 (which measured MfmaUtil 29%, conflicts 0, VALU 6%):
//  (1) MFMA order ks-OUTER: acc-reuse distance 1 -> 8 (kills dependent-pair
//      latency stalls; R10 issued ks=0,1 back-to-back on the same acc).
//  (2) bv double-buffered in registers: tap T+1's 8 LDS frags read before
//      MFMA(T) (same resident chunk, no barrier crossing); per-chunk prologue
//      reads tap0. lgkm latency hides under the MFMA cluster.
//  (3) tap issue order: LDBV(T+1), STB, APREF(T+1), MFMA(T); compiler emits
//      counted lgkm/vm waits per-set.
template <int EPI>
__global__ __launch_bounds__(256, 2) void conv3x3_k(const bf16_t* __restrict__ inp,
                                                    const bf16_t* __restrict__ wts,
                                                    const float* __restrict__ prm,
                                                    const float* __restrict__ resid,
                                                    bf16_t* __restrict__ out_cl,
                                                    float* __restrict__ out_f) {
  __shared__ __align__(128) bf16_t Bs[2][12288];  // 2 x 24 KB (1360 real + 176 pad granules)

  const int tid  = threadIdx.x;
  const int lane = tid & 63;
  const int wid  = tid >> 6;     // 0..3
  const int wm   = wid >> 1;     // co half of 128 (64 each)
  const int wn   = wid & 1;      // px half (4 rows each)

  const int bid = blockIdx.x;    // 512 = 8 XCD x 64
  const int w   = ((bid & 7) << 6) + (bid >> 3);
  const int co0 = (w & 1) << 7;
  const int pt  = w >> 1;        // 256 px tiles
  const int n   = pt >> 2;
  const int hb  = (pt & 3) << 3; // padded top row of the 10-row patch

  const int l31 = lane & 31;
  const int k5  = lane >> 5;

  const long aBase = (long)(co0 + wm * 64 + l31) * CCH + k5 * 8;
  const int  bBase = k5 * 2720 + wn * 1088 + l31 * 8;

  int bofs[6];
#pragma unroll
  for (int j = 0; j < 6; ++j) {
    int idx = j * 256 + tid;
    if (idx > 1359) idx = 1359;                  // source clamp; dest tail -> pad
    const int g   = idx / 340;
    const int rem = idx - g * 340;
    const int r   = rem / 34;
    const int cc  = rem - r * 34;
    bofs[j] = (n * PLANE + (hb + r) * HP + cc) * CCH + g * 8;
  }

  f32x16 acc[2][4];
#pragma unroll
  for (int i = 0; i < 2; ++i)
#pragma unroll
    for (int j = 0; j < 4; ++j)
#pragma unroll
      for (int e = 0; e < 16; ++e) acc[i][j][e] = 0.f;

  bf16x8 avA[4], avB[4];         // A sets (tap parity)
  bf16x8 bvA[8], bvB[8];         // B sets (tap parity: even tap -> bvA)

#define STB(BBUF, CI0N, J) do {                                                      \
    const bf16_t* gb_ = inp + bofs[J] + (CI0N);                                      \
    __builtin_amdgcn_global_load_lds((const AS_GLOBAL void*)gb_,                     \
        (AS_LDS void*)(&Bs[BBUF][((J) * 256 + tid) * 8]), 16, 0, 0);                 \
  } while (0)

#define APREF(SET, CI0N, TT) do {                                                    \
    _Pragma("unroll") for (int mi = 0; mi < 2; ++mi)                                 \
    _Pragma("unroll") for (int ks = 0; ks < 2; ++ks)                                 \
      SET[mi * 2 + ks] = *(const bf16x8*)(wts + (long)(TT) * 65536 + aBase           \
                                          + mi * 8192 + (CI0N) + ks * 16);           \
  } while (0)

#define LDBV(BV, T) do {                                                             \
    constexpr int KH_ = (T) / 3, KW_ = (T) % 3;                                      \
    _Pragma("unroll") for (int nj = 0; nj < 4; ++nj)                                 \
    _Pragma("unroll") for (int ks = 0; ks < 2; ++ks)                                 \
      BV[nj * 2 + ks] = *(const bf16x8*)&bsrd[bBase + ks * 5440                      \
                                              + (nj + KH_) * 272 + KW_ * 8];         \
  } while (0)

  // ks OUTER: consecutive MFMAs hit distinct acc registers (reuse distance 8)
#define MFMA16(ASET, BSET) do {                                                      \
    _Pragma("unroll") for (int ks = 0; ks < 2; ++ks)                                 \
    _Pragma("unroll") for (int mi = 0; mi < 2; ++mi)                                 \
    _Pragma("unroll") for (int nj = 0; nj < 4; ++nj)                                 \
      acc[mi][nj] = __builtin_amdgcn_mfma_f32_32x32x16_bf16(                         \
          ASET[mi * 2 + ks], BSET[nj * 2 + ks], acc[mi][nj], 0, 0, 0);               \
  } while (0)

  // one tap. T/PAR/LASTC literal, c runtime.
  // A set for tap T = (PAR+T)&1 ? avB : avA.  B set for tap T = (T&1) ? bvB : bvA.
#define TAPB(T, PAR, LASTC) do {                                                     \
    if ((T) < 8) {                                                                   \
      if ((T) & 1) { LDBV(bvA, (T) + 1); } else { LDBV(bvB, (T) + 1); }              \
    }                                                                                \
    if (!(LASTC) && (T) <= 5) STB((c + 1) & 1, (c + 1) << 5, T);                     \
    if (!((LASTC) && (T) == 8)) {                                                    \
      constexpr int TN = ((T) + 1) % 9;                                              \
      const int cin = ((T) == 8) ? ((c + 1) << 5) : (c << 5);                        \
      if (((PAR) + (T)) & 1) { APREF(avA, cin, TN); } else { APREF(avB, cin, TN); }  \
    }                                                                                \
    __builtin_amdgcn_s_setprio(1);                                                   \
    if (((PAR) + (T)) & 1) {                                                         \
      if ((T) & 1) { MFMA16(avB, bvB); } else { MFMA16(avB, bvA); }                  \
    } else {                                                                         \
      if ((T) & 1) { MFMA16(avA, bvB); } else { MFMA16(avA, bvA); }                  \
    }                                                                                \
    __builtin_amdgcn_s_setprio(0);                                                   \
  } while (0)

#define CHUNKB(PAR, LASTC) do {                                                      \
    const bf16_t* bsrd = &Bs[c & 1][0];                                              \
    LDBV(bvA, 0);                              /* chunk prologue: tap0 frags */      \
    TAPB(0, PAR, LASTC); TAPB(1, PAR, LASTC); TAPB(2, PAR, LASTC);                   \
    TAPB(3, PAR, LASTC); TAPB(4, PAR, LASTC); TAPB(5, PAR, LASTC);                   \
    TAPB(6, PAR, LASTC); TAPB(7, PAR, LASTC); TAPB(8, PAR, LASTC);                   \
    if (!(LASTC)) { VMW(0); __builtin_amdgcn_s_barrier(); }                          \
  } while (0)

  // prologue: B(chunk0) all 6 pieces; A(tap0) into set A; drain; barrier
  STB(0, 0, 0); STB(0, 0, 1); STB(0, 0, 2); STB(0, 0, 3); STB(0, 0, 4); STB(0, 0, 5);
  APREF(avA, 0, 0);
  VMW(0);
  __builtin_amdgcn_s_barrier();

  int c = 0;
#pragma unroll 1
  for (int it = 0; it < 3; ++it) {
    CHUNKB(0, 0); ++c;
    CHUNKB(1, 0); ++c;
  }
  CHUNKB(0, 0); ++c;          // c = 6
  CHUNKB(1, 1);               // c = 7 tail

#undef TAPB
#undef CHUNKB
#undef APREF
#undef LDBV
#undef MFMA16
#undef STB

  // C/D 32x32 layout: col = lane&31, row = (reg&3) + 8*(reg>>2) + 4*(lane>>5)
  if (EPI == 0) {
#pragma unroll
    for (int mi = 0; mi < 2; ++mi)
#pragma unroll
      for (int nj = 0; nj < 4; ++nj) {
        const int prow = hb + wn * 4 + nj;              // unpadded px row
        const long pbase = ((long)n * PLANE + (prow + 1) * HP + l31 + 1) * CCH;
#pragma unroll
        for (int q = 0; q < 4; ++q) {
          const int co_b = co0 + wm * 64 + mi * 32 + q * 8 + k5 * 4;
          const float s0 = prm[co_b], s1 = prm[co_b + 1], s2 = prm[co_b + 2], s3 = prm[co_b + 3];
          const float t0 = prm[256 + co_b], t1 = prm[256 + co_b + 1],
                      t2 = prm[256 + co_b + 2], t3 = prm[256 + co_b + 3];
          bf16x4 pk;
          pk[0] = (bf16_t)fmaxf(acc[mi][nj][q * 4 + 0] * s0 + t0, 0.f);
          pk[1] = (bf16_t)fmaxf(acc[mi][nj][q * 4 + 1] * s1 + t1, 0.f);
          pk[2] = (bf16_t)fmaxf(acc[mi][nj][q * 4 + 2] * s2 + t2, 0.f);
          pk[3] = (bf16_t)fmaxf(acc[mi][nj][q * 4 + 3] * s3 + t3, 0.f);
          *(bf16x4*)&out_cl[pbase + co_b] = pk;
        }
      }
  } else {
#pragma unroll
    for (int mi = 0; mi < 2; ++mi)
#pragma unroll
      for (int nj = 0; nj < 4; ++nj) {
        const int prow = hb + wn * 4 + nj;
        const int ppos = prow * 32 + l31;
#pragma unroll
        for (int q = 0; q < 4; ++q) {
          const int co_b = co0 + wm * 64 + mi * 32 + q * 8 + k5 * 4;
#pragma unroll
          for (int e = 0; e < 4; ++e) {
            const long gp = (((long)n * CCH + co_b + e) << 10) + ppos;
            out_f[gp] = acc[mi][nj][q * 4 + e] + resid[gp];
          }
        }
      }
  }
}

extern "C" void kernel_launch(void* const* d_in, const int* in_sizes, int n_in,
                              void* d_out, int out_size, void* d_ws, size_t ws_size,
                              hipStream_t stream) {
  const float* x  = (const float*)d_in[0];
  const float* g1 = (const float*)d_in[1];
  const float* b1 = (const float*)d_in[2];
  const float* m1 = (const float*)d_in[3];
  const float* v1 = (const float*)d_in[4];
  const float* w1 = (const float*)d_in[5];
  const float* k1 = (const float*)d_in[6];
  const float* g2 = (const float*)d_in[7];
  const float* b2 = (const float*)d_in[8];
  const float* m2 = (const float*)d_in[9];
  const float* v2 = (const float*)d_in[10];
  const float* w2 = (const float*)d_in[11];
  const float* k2 = (const float*)d_in[12];

  char* ws = (char*)d_ws;
  const size_t T0P_B = (size_t)64 * PLANE * CCH * 2;
  bf16_t* t0p = (bf16_t*)ws;
  bf16_t* t1p = (bf16_t*)(ws + T0P_B);
  bf16_t* mw1 = (bf16_t*)(ws + 2 * T0P_B);
  bf16_t* mw2 = (bf16_t*)(ws + 2 * T0P_B + 1179648);
  float*  prm = (float*)(ws + 2 * T0P_B + 2 * 1179648);

  prep_params_k<<<1, 256, 0, stream>>>(g1, b1, m1, v1, g2, b2, m2, v2, prm);
  zero_borders_k<<<128, 256, 0, stream>>>(t0p, t1p);
  prep_weights_k<<<256, 256, 0, stream>>>(w1, k1, mw1);
  prep_weights_k<<<256, 256, 0, stream>>>(w2, k2, mw2);
  prep_input_k<<<1024, 256, 0, stream>>>(x, prm, t0p);

  conv3x3_k<0><<<512, 256, 0, stream>>>(t0p, mw1, prm + 512, nullptr, t1p, nullptr);
  conv3x3_k<1><<<512, 256, 0, stream>>>(t1p, mw2, nullptr, x, nullptr, (float*)d_out);
}

// Round 12
// 222.693 us; speedup vs baseline: 1.0756x; 1.0756x over previous
//
#include <hip/hip_runtime.h>
#include <hip/hip_bf16.h>
#include <stdint.h>

typedef __bf16 bf16_t;
typedef __bf16 bf16x8 __attribute__((ext_vector_type(8)));
typedef __bf16 bf16x4 __attribute__((ext_vector_type(4)));
typedef float  f32x4  __attribute__((ext_vector_type(4)));
typedef float  f32x16 __attribute__((ext_vector_type(16)));

#define AS_GLOBAL __attribute__((address_space(1)))
#define AS_LDS    __attribute__((address_space(3)))
#define VMW(N) asm volatile("s_waitcnt vmcnt(" #N ")" ::: "memory")

static constexpr int CCH   = 256;
static constexpr int HP    = 34;
static constexpr int PLANE = HP * HP;   // 1156 padded pixels per image

// ---------------- BN parameter folding ----------------
__global__ void prep_params_k(const float* g1, const float* b1, const float* m1, const float* v1,
                              const float* g2, const float* b2, const float* m2, const float* v2,
                              float* prm) {
  int i = threadIdx.x;
  float i1 = g1[i] * rsqrtf(v1[i] + 1e-5f);
  prm[i]       = i1;
  prm[256 + i] = b1[i] - m1[i] * i1;
  float i2 = g2[i] * rsqrtf(v2[i] + 1e-5f);
  prm[512 + i] = i2;
  prm[768 + i] = b2[i] - m2[i] * i2;
}

// ---------------- masked weights -> bf16, [khw][co][ci] ----------------
__global__ __launch_bounds__(256) void prep_weights_k(const float* __restrict__ w,
                                                      const float* __restrict__ msk,
                                                      bf16_t* __restrict__ out) {
  int idx = blockIdx.x * 256 + threadIdx.x;
  const float* wp = w + (long)idx * 9;
  const float* mp = msk + (long)idx * 9;
#pragma unroll
  for (int khw = 0; khw < 9; ++khw)
    out[khw * 65536 + idx] = (bf16_t)(wp[khw] * mp[khw]);
}

// ---------------- zero only the pad borders of both intermediates ----------------
__global__ __launch_bounds__(256) void zero_borders_k(bf16_t* __restrict__ t0p,
                                                      bf16_t* __restrict__ t1p) {
  const int bid = blockIdx.x;               // 128: image n = bid>>1, buffer = bid&1
  bf16_t* base = ((bid & 1) ? t1p : t0p) + (long)(bid >> 1) * PLANE * CCH;
  for (int i = threadIdx.x; i < 132 * 32; i += 256) {
    int pix = i >> 5, c16 = i & 31;
    int r, col;
    if (pix < 34)       { r = 0;           col = pix; }
    else if (pix < 68)  { r = 33;          col = pix - 34; }
    else if (pix < 100) { r = pix - 68 + 1; col = 0; }
    else                { r = pix - 100 + 1; col = 33; }
    *(f32x4*)&base[(r * HP + col) * CCH + c16 * 8] = f32x4{0.f, 0.f, 0.f, 0.f};
  }
}

// ------- relu(bn1(x)) -> bf16, NCHW -> channels-last padded [n][34*34][256] -------
__global__ __launch_bounds__(256) void prep_input_k(const float* __restrict__ x,
                                                    const float* __restrict__ prm,
                                                    bf16_t* __restrict__ t0p) {
  __shared__ __align__(16) bf16_t tile[64 * 256];
  const int tid = threadIdx.x;
  const int bid = blockIdx.x;
  const int n   = bid >> 4;
  const int p0  = (bid & 15) << 6;
  const int px    = tid & 63;
  const int cbase = tid >> 6;
  for (int r = 0; r < 64; ++r) {
    int ci = r * 4 + cbase;
    float v = x[((n * 256 + ci) << 10) + p0 + px];
    float y = fmaxf(v * prm[ci] + prm[256 + ci], 0.f);
    int byte = px * 512 + ((ci * 2) ^ ((px & 7) << 4));
    *(bf16_t*)((char*)tile + byte) = (bf16_t)y;
  }
  __syncthreads();
  for (int j = 0; j < 8; ++j) {
    int off  = j * 256 + tid;
    int pix  = off >> 5;
    int c16  = off & 31;
    int byte = pix * 512 + ((c16 * 16) ^ ((pix & 7) << 4));
    bf16x8 v = *(const bf16x8*)((char*)tile + byte);
    int p = p0 + pix;
    long gp = ((long)n * PLANE + ((p >> 5) + 1) * HP + (p & 31) + 1) * CCH + c16 * 8;
    *(bf16x8*)(t0p + gp) = v;
  }
}

// ---- implicit-GEMM 3x3 conv: A global->VGPR, B plane-major LDS, 32x32 MFMA ------
// Block 128co x 256px, 4 waves, wave 64co x 128px (2x4 tiles of 32x32).
// R12 = R10 + ks-OUTER orderings ONLY (register-neutral; R11's bv-dbuf spilled):
//  - LDBV issues ks0 frags (bv[0,2,4,6]) then ks1 -> compiler's counted lgkmcnt
//    lets the ks0 MFMA half start after 4 returns.
//  - MFMA16 runs ks outer: 8 independent MFMAs per half, acc-reuse distance 8
//    (~68 cyc pipe) > MFMA latency -> no dependent-pair stalls (R10 issued
//    ks0,ks1 back-to-back on the same accumulator).
template <int EPI>
__global__ __launch_bounds__(256, 2) void conv3x3_k(const bf16_t* __restrict__ inp,
                                                    const bf16_t* __restrict__ wts,
                                                    const float* __restrict__ prm,
                                                    const float* __restrict__ resid,
                                                    bf16_t* __restrict__ out_cl,
                                                    float* __restrict__ out_f) {
  __shared__ __align__(128) bf16_t Bs[2][12288];  // 2 x 24 KB (1360 real + 176 pad granules)

  const int tid  = threadIdx.x;
  const int lane = tid & 63;
  const int wid  = tid >> 6;     // 0..3
  const int wm   = wid >> 1;     // co half of 128 (64 each)
  const int wn   = wid & 1;      // px half (4 rows each)

  const int bid = blockIdx.x;    // 512 = 8 XCD x 64
  const int w   = ((bid & 7) << 6) + (bid >> 3);
  const int co0 = (w & 1) << 7;
  const int pt  = w >> 1;        // 256 px tiles
  const int n   = pt >> 2;
  const int hb  = (pt & 3) << 3; // padded top row of the 10-row patch

  const int l31 = lane & 31;
  const int k5  = lane >> 5;

  const long aBase = (long)(co0 + wm * 64 + l31) * CCH + k5 * 8;
  const int  bBase = k5 * 2720 + wn * 1088 + l31 * 8;

  int bofs[6];
#pragma unroll
  for (int j = 0; j < 6; ++j) {
    int idx = j * 256 + tid;
    if (idx > 1359) idx = 1359;                  // source clamp; dest tail -> pad
    const int g   = idx / 340;
    const int rem = idx - g * 340;
    const int r   = rem / 34;
    const int cc  = rem - r * 34;
    bofs[j] = (n * PLANE + (hb + r) * HP + cc) * CCH + g * 8;
  }

  f32x16 acc[2][4];
#pragma unroll
  for (int i = 0; i < 2; ++i)
#pragma unroll
    for (int j = 0; j < 4; ++j)
#pragma unroll
      for (int e = 0; e < 16; ++e) acc[i][j][e] = 0.f;

  bf16x8 avA[4], avB[4], bv[8];

#define STB(BBUF, CI0N, J) do {                                                      \
    const bf16_t* gb_ = inp + bofs[J] + (CI0N);                                      \
    __builtin_amdgcn_global_load_lds((const AS_GLOBAL void*)gb_,                     \
        (AS_LDS void*)(&Bs[BBUF][((J) * 256 + tid) * 8]), 16, 0, 0);                 \
  } while (0)

#define APREF(SET, CI0N, TT) do {                                                    \
    _Pragma("unroll") for (int mi = 0; mi < 2; ++mi)                                 \
    _Pragma("unroll") for (int ks = 0; ks < 2; ++ks)                                 \
      SET[mi * 2 + ks] = *(const bf16x8*)(wts + (long)(TT) * 65536 + aBase           \
                                          + mi * 8192 + (CI0N) + ks * 16);           \
  } while (0)

  // ks OUTER load order: ks0 frags first -> MFMA ks0 half can start early
#define LDBV(T) do {                                                                 \
    constexpr int KH_ = (T) / 3, KW_ = (T) % 3;                                      \
    _Pragma("unroll") for (int ks = 0; ks < 2; ++ks)                                 \
    _Pragma("unroll") for (int nj = 0; nj < 4; ++nj)                                 \
      bv[nj * 2 + ks] = *(const bf16x8*)&bsrd[bBase + ks * 5440                      \
                                              + (nj + KH_) * 272 + KW_ * 8];         \
  } while (0)

  // ks OUTER: consecutive MFMAs hit distinct acc registers (reuse distance 8)
#define MFMA16(SET) do {                                                             \
    _Pragma("unroll") for (int ks = 0; ks < 2; ++ks)                                 \
    _Pragma("unroll") for (int mi = 0; mi < 2; ++mi)                                 \
    _Pragma("unroll") for (int nj = 0; nj < 4; ++nj)                                 \
      acc[mi][nj] = __builtin_amdgcn_mfma_f32_32x32x16_bf16(                         \
          SET[mi * 2 + ks], bv[nj * 2 + ks], acc[mi][nj], 0, 0, 0);                  \
  } while (0)

  // one tap. T/PAR/LASTC literal, c runtime. A-set used = (PAR+T)&1 ? avB : avA.
#define TAPB(T, PAR, LASTC) do {                                                     \
    LDBV(T);                                                                         \
    if (!(LASTC) && (T) <= 5) STB((c + 1) & 1, (c + 1) << 5, T);                     \
    if (!((LASTC) && (T) == 8)) {                                                    \
      constexpr int TN = ((T) + 1) % 9;                                              \
      const int cin = ((T) == 8) ? ((c + 1) << 5) : (c << 5);                        \
      if (((PAR) + (T)) & 1) { APREF(avA, cin, TN); } else { APREF(avB, cin, TN); }  \
    }                                                                                \
    __builtin_amdgcn_s_setprio(1);                                                   \
    if (((PAR) + (T)) & 1) { MFMA16(avB); } else { MFMA16(avA); }                    \
    __builtin_amdgcn_s_setprio(0);                                                   \
  } while (0)

#define CHUNKB(PAR, LASTC) do {                                                      \
    const bf16_t* bsrd = &Bs[c & 1][0];                                              \
    TAPB(0, PAR, LASTC); TAPB(1, PAR, LASTC); TAPB(2, PAR, LASTC);                   \
    TAPB(3, PAR, LASTC); TAPB(4, PAR, LASTC); TAPB(5, PAR, LASTC);                   \
    TAPB(6, PAR, LASTC); TAPB(7, PAR, LASTC); TAPB(8, PAR, LASTC);                   \
    if (!(LASTC)) { VMW(0); __builtin_amdgcn_s_barrier(); }                          \
  } while (0)

  // prologue: B(chunk0) all 6 pieces; A(tap0) into set A; drain; barrier
  STB(0, 0, 0); STB(0, 0, 1); STB(0, 0, 2); STB(0, 0, 3); STB(0, 0, 4); STB(0, 0, 5);
  APREF(avA, 0, 0);
  VMW(0);
  __builtin_amdgcn_s_barrier();

  int c = 0;
#pragma unroll 1
  for (int it = 0; it < 3; ++it) {
    CHUNKB(0, 0); ++c;
    CHUNKB(1, 0); ++c;
  }
  CHUNKB(0, 0); ++c;          // c = 6
  CHUNKB(1, 1);               // c = 7 tail

#undef TAPB
#undef CHUNKB
#undef APREF
#undef LDBV
#undef MFMA16
#undef STB

  // C/D 32x32 layout: col = lane&31, row = (reg&3) + 8*(reg>>2) + 4*(lane>>5)
  if (EPI == 0) {
#pragma unroll
    for (int mi = 0; mi < 2; ++mi)
#pragma unroll
      for (int nj = 0; nj < 4; ++nj) {
        const int prow = hb + wn * 4 + nj;              // unpadded px row
        const long pbase = ((long)n * PLANE + (prow + 1) * HP + l31 + 1) * CCH;
#pragma unroll
        for (int q = 0; q < 4; ++q) {
          const int co_b = co0 + wm * 64 + mi * 32 + q * 8 + k5 * 4;
          const float s0 = prm[co_b], s1 = prm[co_b + 1], s2 = prm[co_b + 2], s3 = prm[co_b + 3];
          const float t0 = prm[256 + co_b], t1 = prm[256 + co_b + 1],
                      t2 = prm[256 + co_b + 2], t3 = prm[256 + co_b + 3];
          bf16x4 pk;
          pk[0] = (bf16_t)fmaxf(acc[mi][nj][q * 4 + 0] * s0 + t0, 0.f);
          pk[1] = (bf16_t)fmaxf(acc[mi][nj][q * 4 + 1] * s1 + t1, 0.f);
          pk[2] = (bf16_t)fmaxf(acc[mi][nj][q * 4 + 2] * s2 + t2, 0.f);
          pk[3] = (bf16_t)fmaxf(acc[mi][nj][q * 4 + 3] * s3 + t3, 0.f);
          *(bf16x4*)&out_cl[pbase + co_b] = pk;
        }
      }
  } else {
#pragma unroll
    for (int mi = 0; mi < 2; ++mi)
#pragma unroll
      for (int nj = 0; nj < 4; ++nj) {
        const int prow = hb + wn * 4 + nj;
        const int ppos = prow * 32 + l31;
#pragma unroll
        for (int q = 0; q < 4; ++q) {
          const int co_b = co0 + wm * 64 + mi * 32 + q * 8 + k5 * 4;
#pragma unroll
          for (int e = 0; e < 4; ++e) {
            const long gp = (((long)n * CCH + co_b + e) << 10) + ppos;
            out_f[gp] = acc[mi][nj][q * 4 + e] + resid[gp];
          }
        }
      }
  }
}

extern "C" void kernel_launch(void* const* d_in, const int* in_sizes, int n_in,
                              void* d_out, int out_size, void* d_ws, size_t ws_size,
                              hipStream_t stream) {
  const float* x  = (const float*)d_in[0];
  const float* g1 = (const float*)d_in[1];
  const float* b1 = (const float*)d_in[2];
  const float* m1 = (const float*)d_in[3];
  const float* v1 = (const float*)d_in[4];
  const float* w1 = (const float*)d_in[5];
  const float* k1 = (const float*)d_in[6];
  const float* g2 = (const float*)d_in[7];
  const float* b2 = (const float*)d_in[8];
  const float* m2 = (const float*)d_in[9];
  const float* v2 = (const float*)d_in[10];
  const float* w2 = (const float*)d_in[11];
  const float* k2 = (const float*)d_in[12];

  char* ws = (char*)d_ws;
  const size_t T0P_B = (size_t)64 * PLANE * CCH * 2;
  bf16_t* t0p = (bf16_t*)ws;
  bf16_t* t1p = (bf16_t*)(ws + T0P_B);
  bf16_t* mw1 = (bf16_t*)(ws + 2 * T0P_B);
  bf16_t* mw2 = (bf16_t*)(ws + 2 * T0P_B + 1179648);
  float*  prm = (float*)(ws + 2 * T0P_B + 2 * 1179648);

  prep_params_k<<<1, 256, 0, stream>>>(g1, b1, m1, v1, g2, b2, m2, v2, prm);
  zero_borders_k<<<128, 256, 0, stream>>>(t0p, t1p);
  prep_weights_k<<<256, 256, 0, stream>>>(w1, k1, mw1);
  prep_weights_k<<<256, 256, 0, stream>>>(w2, k2, mw2);
  prep_input_k<<<1024, 256, 0, stream>>>(x, prm, t0p);

  conv3x3_k<0><<<512, 256, 0, stream>>>(t0p, mw1, prm + 512, nullptr, t1p, nullptr);
  conv3x3_k<1><<<512, 256, 0, stream>>>(t1p, mw2, nullptr, x, nullptr, (float*)d_out);
}